// Round 5
// baseline (5075.646 us; speedup 1.0000x reference)
//
#include <hip/hip_runtime.h>
#include <cstdint>
#include <cstddef>

// ============================================================================
// LSTM forecaster, MI355X — R9: R8 + flag-gated polling (sentinel kept as net).
// R7/R8 evidence: two different compute organizations both ~5650cy/step ->
// compute is not the bottleneck; wait ~4500cy vs ~1800cy naive latency model.
// Theory: all-thread data-polling (bypass atomics, 16KB/block/iteration) puts
// ~10+ TB/s of spin reads through the LLC coherence point -> latency inflation.
// R9: producer wave stores its 128B h line, then lane0 stores flag[g][fq]=t
// (relaxed agent, no waitcnt — sentinel loop catches flag/data reorder).
// Consumers spin on 4 flags (shared dwords, coalesced, ~64x less traffic),
// then load data with the same atomic+sentinel fallback as before (now rare).
// Everything else identical to R8 (1-barrier step, [t][fq][b][4] h layout).
// ============================================================================

typedef __bf16 bf16x8 __attribute__((ext_vector_type(8)));
typedef float  f32x4  __attribute__((ext_vector_type(4)));

static constexpr unsigned long long SENT = 0x7FC07FC07FC07FC0ULL;  // 4x bf16 NaN

// ---- workspace layout (bytes) ----
static constexpr size_t SZ_HALL = (size_t)705 * 128 * 512 * 2;  // h slots 0..704
static constexpr size_t SZ_WCAT = (size_t)2048 * 576 * 2;       // [Whh | Wfuse] bf16
static constexpr size_t SZ_WIH  = (size_t)2048 * 512 * 2;       // Wih bf16 (AR phase)
static constexpr size_t SZ_DECW = (size_t)64 * 512 * 2;         // dec_W bf16
static constexpr size_t SZ_XT   = (size_t)512 * 128 * 64 * 2;   // x transposed [t][b][c]
static constexpr size_t OFF_HALL = 0;
static constexpr size_t OFF_WCAT = OFF_HALL + SZ_HALL;
static constexpr size_t OFF_WIH  = OFF_WCAT + SZ_WCAT;
static constexpr size_t OFF_DECW = OFF_WIH + SZ_WIH;
static constexpr size_t OFF_XT   = OFF_DECW + SZ_DECW;
static constexpr size_t OFF_B2   = OFF_XT + SZ_XT;              // 2048 f32
static constexpr size_t OFF_BAR_ = OFF_B2 + 2048 * 4;           // b_ar 2048 f32
static constexpr size_t OFF_FLAG = OFF_BAR_ + 2048 * 4;         // flags[8][128] u32
static constexpr size_t WS_NEEDED = OFF_FLAG + 1024 * 4;

__device__ __forceinline__ float sigm(float x) { return 1.f / (1.f + __expf(-x)); }
__device__ __forceinline__ float tanh_fast(float x) {
  return 1.f - 2.f / (__expf(2.f * x) + 1.f);  // correct +/-1 limits on over/underflow
}

// h element (t, b, f) lives at h_all[t*65536 + (f>>2)*512 + b*4 + (f&3)]
// -> one 128B line = [t][fq][b0..b0+15][0..3]: 16 batches x 4 feats, owned by
//    exactly one producer wave, guarded by flags[g][fq] >= t.

// ---------------------------------------------------------------------------
// setup0: conversions + h slot0 zeros + h slots 1..704 NaN sentinel + flag=0.
// ---------------------------------------------------------------------------
__global__ void __launch_bounds__(256)
setup0(const float* __restrict__ x, const float* __restrict__ Wih,
       const float* __restrict__ Whh, const float* __restrict__ bih,
       const float* __restrict__ bhh, const float* __restrict__ decW,
       __bf16* __restrict__ xT, __bf16* __restrict__ Wih_bf,
       __bf16* __restrict__ Wcat, __bf16* __restrict__ decW_bf,
       float* __restrict__ b_ar, __bf16* __restrict__ h_all,
       unsigned* __restrict__ flags)
{
  size_t gid = (size_t)blockIdx.x * blockDim.x + threadIdx.x;
  size_t gsz = (size_t)gridDim.x * blockDim.x;
  for (size_t i = gid; i < 4194304u; i += gsz) {          // xT[t][b][c] = x[b][t][c]
    size_t t = i >> 13, b = (i >> 6) & 127u, c = i & 63u;
    xT[i] = (__bf16)x[(b * 512 + t) * 64 + c];
  }
  for (size_t i = gid; i < 1048576u; i += gsz) Wih_bf[i] = (__bf16)Wih[i];
  for (size_t i = gid; i < 1048576u; i += gsz) {
    size_t r = i >> 9, k = i & 511u;
    Wcat[r * 576 + k] = (__bf16)Whh[i];                   // cols 0..511 = Whh
  }
  for (size_t i = gid; i < 32768u; i += gsz) decW_bf[i] = (__bf16)decW[i];
  for (size_t i = gid; i < 2048u; i += gsz) b_ar[i] = bih[i] + bhh[i];
  for (size_t i = gid; i < 1024u; i += gsz) flags[i] = 0u;  // flags must start 0
  unsigned long long* hp = (unsigned long long*)h_all;
  for (size_t i = gid; i < 16384u; i += gsz) hp[i] = 0ULL;               // slot 0 = 0
  for (size_t i = 16384u + gid; i < 11550720u; i += gsz) hp[i] = SENT;   // slots 1..704
}

// ---------------------------------------------------------------------------
// setup1: Wfuse = Wih @ enc_W -> Wcat cols 512..575 ; b2 = bih+bhh+Wih@enc_b
// ---------------------------------------------------------------------------
__global__ void __launch_bounds__(64)
setup1(const float* __restrict__ Wih, const float* __restrict__ encW,
       const float* __restrict__ encb, const float* __restrict__ bih,
       const float* __restrict__ bhh, __bf16* __restrict__ Wcat,
       float* __restrict__ b2)
{
  int r = blockIdx.x;        // 0..2047
  int c = threadIdx.x;       // 0..63
  const float* wr = Wih + (size_t)r * 512;
  float acc = 0.f;
  for (int k = 0; k < 512; ++k) acc += wr[k] * encW[(size_t)k * 64 + c];
  Wcat[(size_t)r * 576 + 512 + c] = (__bf16)acc;
  float p = 0.f;
  for (int kk = 0; kk < 8; ++kk) { int k = kk * 64 + c; p += wr[k] * encb[k]; }
  for (int off = 32; off > 0; off >>= 1) p += __shfl_down(p, off);
  if (c == 0) b2[r] = bih[r] + bhh[r] + p;
}

// ---------------------------------------------------------------------------
// One LSTM step. block = 512 thr (8 waves). Identical to R8 except the poll
// is flag-gated: thread (wv,quad,n16) first spins on flags[g][fq..fq+3]
// (fq = wv*16+quad*4) until >= t-1, then does the data loads. The sentinel
// check remains as a correctness net for flag/data store reordering.
// ---------------------------------------------------------------------------
template<bool MAIN>
__device__ __forceinline__ void lstm_step(
    unsigned t, int tid, int wv, int lane, int n16, int quad, int b0, int f0,
    const bf16x8 (&wf)[18], const f32x4& bv,
    __bf16* __restrict__ h_all, const __bf16* __restrict__ xT,
    unsigned* __restrict__ flags, float& creg, __bf16 (*A)[584])
{
  const int g128 = (b0 >> 4) << 7;           // group g * 128

  // ---- x prefetch (overlaps the flag spin + poll) ----
  uint4 xv;
  if (MAIN && tid < 128)
    xv = *(const uint4*)(xT + (size_t)(t - 1) * 8192 +
                         (size_t)(b0 + (tid >> 3)) * 64 + (tid & 7) * 8);

  // ---- flag spin: 4 dwords shared by 16 lanes -> 1 coalesced request ----
  if (t >= 2) {
    const unsigned need = t - 1;
    const unsigned* fp = flags + g128 + (wv << 4) + (quad << 2);
    unsigned a = __hip_atomic_load(fp + 0, __ATOMIC_RELAXED, __HIP_MEMORY_SCOPE_AGENT);
    unsigned b = __hip_atomic_load(fp + 1, __ATOMIC_RELAXED, __HIP_MEMORY_SCOPE_AGENT);
    unsigned c = __hip_atomic_load(fp + 2, __ATOMIC_RELAXED, __HIP_MEMORY_SCOPE_AGENT);
    unsigned d = __hip_atomic_load(fp + 3, __ATOMIC_RELAXED, __HIP_MEMORY_SCOPE_AGENT);
    while (a < need || b < need || c < need || d < need) {
      if (a < need) a = __hip_atomic_load(fp + 0, __ATOMIC_RELAXED, __HIP_MEMORY_SCOPE_AGENT);
      if (b < need) b = __hip_atomic_load(fp + 1, __ATOMIC_RELAXED, __HIP_MEMORY_SCOPE_AGENT);
      if (c < need) c = __hip_atomic_load(fp + 2, __ATOMIC_RELAXED, __HIP_MEMORY_SCOPE_AGENT);
      if (d < need) d = __hip_atomic_load(fp + 3, __ATOMIC_RELAXED, __HIP_MEMORY_SCOPE_AGENT);
    }
  }

  // ---- data loads (flag-gated; sentinel loop is the rare fallback) ----
  const unsigned long long* s0 = (const unsigned long long*)
      (h_all + (size_t)(t - 1) * 65536) +
      (size_t)(wv * 16 + (quad << 2)) * 128 + (b0 + n16);
  unsigned long long v0 = __hip_atomic_load(s0,       __ATOMIC_RELAXED, __HIP_MEMORY_SCOPE_AGENT);
  unsigned long long v1 = __hip_atomic_load(s0 + 128, __ATOMIC_RELAXED, __HIP_MEMORY_SCOPE_AGENT);
  unsigned long long v2 = __hip_atomic_load(s0 + 256, __ATOMIC_RELAXED, __HIP_MEMORY_SCOPE_AGENT);
  unsigned long long v3 = __hip_atomic_load(s0 + 384, __ATOMIC_RELAXED, __HIP_MEMORY_SCOPE_AGENT);
  while (v0 == SENT || v1 == SENT || v2 == SENT || v3 == SENT) {
    if (v0 == SENT) v0 = __hip_atomic_load(s0,       __ATOMIC_RELAXED, __HIP_MEMORY_SCOPE_AGENT);
    if (v1 == SENT) v1 = __hip_atomic_load(s0 + 128, __ATOMIC_RELAXED, __HIP_MEMORY_SCOPE_AGENT);
    if (v2 == SENT) v2 = __hip_atomic_load(s0 + 256, __ATOMIC_RELAXED, __HIP_MEMORY_SCOPE_AGENT);
    if (v3 == SENT) v3 = __hip_atomic_load(s0 + 384, __ATOMIC_RELAXED, __HIP_MEMORY_SCOPE_AGENT);
  }

  // ---- stage A: pieces fq..fq+3 -> features fq*4..fq*4+16 of batch n16 ----
  {
    unsigned long long* ad = (unsigned long long*)&A[n16][wv * 64 + (quad << 4)];
    ad[0] = v0; ad[1] = v1; ad[2] = v2; ad[3] = v3;
  }
  if (MAIN && tid < 128)
    *(uint4*)(&A[tid >> 3][512 + (tid & 7) * 8]) = xv;
  __syncthreads();                               // the ONLY barrier per step

  // ---- MFMA: acc regs = 4 gates of this lane's (feature, batch) ----
  f32x4 a0 = bv, a1 = {0.f, 0.f, 0.f, 0.f};
  const __bf16* arow = &A[n16][quad * 8];
  #pragma unroll
  for (int kc = 0; kc < (MAIN ? 18 : 16); ++kc) {
    bf16x8 af = *(const bf16x8*)(arow + kc * 32);
    if (kc & 1) a1 = __builtin_amdgcn_mfma_f32_16x16x32_bf16(wf[kc], af, a1, 0, 0, 0);
    else        a0 = __builtin_amdgcn_mfma_f32_16x16x32_bf16(wf[kc], af, a0, 0, 0, 0);
  }
  a0 += a1;

  // ---- gates in registers ----
  float ig = sigm(a0[0]), gg = tanh_fast(a0[2]), og = sigm(a0[3]);
  float c2;
  if (MAIN) { float fg = sigm(a0[1]); c2 = fg * creg + ig * gg; creg = c2; }
  else      { c2 = ig * gg; }                      // AR: zero state
  unsigned hbits = __builtin_bit_cast(unsigned short, (__bf16)(og * tanh_fast(c2)));

  // ---- quad-gather + full-line publish by 16 lanes, then release flag ----
  unsigned long long pk = 0;
  #pragma unroll
  for (int q = 0; q < 4; ++q)
    pk |= (unsigned long long)(unsigned short)__shfl((int)hbits, q * 16 + n16) << (16 * q);
  const int fq = (f0 >> 2) + wv;
  if (lane < 16) {
    unsigned long long* dst = (unsigned long long*)
        (h_all + (size_t)t * 65536) + (size_t)fq * 128 + (b0 + lane);
    __hip_atomic_store(dst, pk, __ATOMIC_RELAXED, __HIP_MEMORY_SCOPE_AGENT);
  }
  if (lane == 0)   // flag may overtake data on the fabric: sentinel net catches it
    __hip_atomic_store(flags + g128 + fq, t, __ATOMIC_RELAXED, __HIP_MEMORY_SCOPE_AGENT);
  // next step's staging writes go to the OTHER A buffer; its barrier orders
  // them against this step's ds_reads.
}

__global__ void __launch_bounds__(512, 2)
lstm_persist(const __bf16* __restrict__ xT, const __bf16* __restrict__ Wcat,
             const __bf16* __restrict__ Wih_bf, const float* __restrict__ b2,
             const float* __restrict__ b_ar, __bf16* __restrict__ h_all,
             unsigned* __restrict__ flags)
{
  const int bid = blockIdx.x;                  // 128 blocks
  const int g = bid & 7, sub = bid >> 3;       // sub = 0..15
  const int b0 = g * 16, f0 = sub * 32;
  const int tid = threadIdx.x;
  const int wv = tid >> 6, lane = tid & 63;    // wv = 0..7
  const int n16 = lane & 15, quad = lane >> 4;

  __shared__ __align__(16) __bf16 Abuf[2][16][584];  // double-buffered A tile

  // persistent weight fragments, interleaved rows: lane n16 holds tile row
  // n16 = f_local*4+gate -> global row gate*512 + f0 + wv*4 + f_local.
  bf16x8 wf[18];
  f32x4 bv;
  {
    const int gate = n16 & 3, fl = n16 >> 2;
    const __bf16* wrow = Wcat + (size_t)(gate * 512 + f0 + wv * 4 + fl) * 576 + quad * 8;
    #pragma unroll
    for (int kc = 0; kc < 18; ++kc) wf[kc] = *(const bf16x8*)(wrow + kc * 32);
    const int fb = f0 + wv * 4 + quad;         // this lane's feature
    bv = f32x4{b2[fb], b2[512 + fb], b2[1024 + fb], b2[1536 + fb]};
  }

  float creg = 0.f;   // cell state of (feature = f0+wv*4+quad, batch = b0+n16)

  for (unsigned t = 1; t <= 512; ++t)
    lstm_step<true>(t, tid, wv, lane, n16, quad, b0, f0, wf, bv,
                    h_all, xT, flags, creg, Abuf[t & 1]);

  { // AR phase: h feeds Wih with zero recurrent state
    const int gate = n16 & 3, fl = n16 >> 2;
    const __bf16* wrow = Wih_bf + (size_t)(gate * 512 + f0 + wv * 4 + fl) * 512 + quad * 8;
    #pragma unroll
    for (int kc = 0; kc < 16; ++kc) wf[kc] = *(const bf16x8*)(wrow + kc * 32);
    const int fb = f0 + wv * 4 + quad;
    bv = f32x4{b_ar[fb], b_ar[512 + fb], b_ar[1024 + fb], b_ar[1536 + fb]};
  }
  for (unsigned t = 513; t <= 704; ++t)
    lstm_step<false>(t, tid, wv, lane, n16, quad, b0, f0, wf, bv,
                     h_all, xT, flags, creg, Abuf[t & 1]);
}

// ---------------------------------------------------------------------------
// final_proj: out[b][j][c] = h_slot[j+2][b][:] @ dec_W.T + dec_b, j=0..702.
// h layout [t][fq][b][4]: fragment (slot,b, feats f..f+8) = two 8B pieces at
// ull index slot*16384 + fq*128 + b, fq = f>>2 and fq+1.
// ---------------------------------------------------------------------------
__global__ void __launch_bounds__(256)
final_proj(const __bf16* __restrict__ h_all, const __bf16* __restrict__ decW_bf,
           const float* __restrict__ decb, float* __restrict__ out)
{
  const int bi = blockIdx.x;               // 0..702
  const int tid = threadIdx.x;
  const int wv = tid >> 6, lane = tid & 63;
  const int n16 = lane & 15, quad = lane >> 4;
  const size_t r0 = 256 + (size_t)bi * 128 + (size_t)wv * 32;

  union U8 { unsigned long long u[2]; bf16x8 v; };
  const unsigned long long* hq = (const unsigned long long*)h_all;

  // input-row bases for the two m-tiles (rows r0+n16 and r0+16+n16)
  size_t base[2];
  #pragma unroll
  for (int mt = 0; mt < 2; ++mt) {
    size_t Rm = r0 + (size_t)mt * 16 + n16;
    base[mt] = (Rm >> 7) * 16384 + (Rm & 127);
  }

  f32x4 acc[2][4];
  #pragma unroll
  for (int mt = 0; mt < 2; ++mt)
    #pragma unroll
    for (int nt = 0; nt < 4; ++nt) acc[mt][nt] = f32x4{0.f, 0.f, 0.f, 0.f};

  const __bf16* brow = decW_bf + (size_t)n16 * 512 + quad * 8;

  #pragma unroll
  for (int kc = 0; kc < 16; ++kc) {
    const int fq = quad * 2 + kc * 8;
    U8 a0, a1;
    a0.u[0] = hq[base[0] + (size_t)fq * 128];
    a0.u[1] = hq[base[0] + (size_t)(fq + 1) * 128];
    a1.u[0] = hq[base[1] + (size_t)fq * 128];
    a1.u[1] = hq[base[1] + (size_t)(fq + 1) * 128];
    #pragma unroll
    for (int nt = 0; nt < 4; ++nt) {
      bf16x8 b = *(const bf16x8*)(brow + (size_t)nt * 8192 + kc * 32);
      acc[0][nt] = __builtin_amdgcn_mfma_f32_16x16x32_bf16(a0.v, b, acc[0][nt], 0, 0, 0);
      acc[1][nt] = __builtin_amdgcn_mfma_f32_16x16x32_bf16(a1.v, b, acc[1][nt], 0, 0, 0);
    }
  }
  #pragma unroll
  for (int mt = 0; mt < 2; ++mt)
    #pragma unroll
    for (int nt = 0; nt < 4; ++nt)
      #pragma unroll
      for (int r = 0; r < 4; ++r) {
        size_t R = r0 + mt * 16 + quad * 4 + r;      // h row (slot,b)
        int slot = (int)(R >> 7), b = (int)(R & 127);
        int j = slot - 2;
        int c = nt * 16 + n16;
        out[((size_t)b * 703 + j) * 64 + c] = acc[mt][nt][r] + decb[c];
      }
}

// ---------------------------------------------------------------------------
extern "C" void kernel_launch(void* const* d_in, const int* in_sizes, int n_in,
                              void* d_out, int out_size, void* d_ws, size_t ws_size,
                              hipStream_t stream)
{
  const float* x    = (const float*)d_in[0];
  const float* encW = (const float*)d_in[1];
  const float* encb = (const float*)d_in[2];
  const float* Wih  = (const float*)d_in[3];
  const float* Whh  = (const float*)d_in[4];
  const float* bih  = (const float*)d_in[5];
  const float* bhh  = (const float*)d_in[6];
  const float* decW = (const float*)d_in[7];
  const float* decb = (const float*)d_in[8];
  float* out = (float*)d_out;

  if (ws_size < WS_NEEDED) return;

  char* ws = (char*)d_ws;
  __bf16* h_all   = (__bf16*)(ws + OFF_HALL);
  __bf16* Wcat    = (__bf16*)(ws + OFF_WCAT);
  __bf16* Wih_bf  = (__bf16*)(ws + OFF_WIH);
  __bf16* decW_bf = (__bf16*)(ws + OFF_DECW);
  __bf16* xT      = (__bf16*)(ws + OFF_XT);
  float*  b2      = (float*)(ws + OFF_B2);
  float*  b_ar    = (float*)(ws + OFF_BAR_);
  unsigned* flags = (unsigned*)(ws + OFF_FLAG);

  hipLaunchKernelGGL(setup0, dim3(2048), dim3(256), 0, stream,
                     x, Wih, Whh, bih, bhh, decW, xT, Wih_bf, Wcat, decW_bf,
                     b_ar, h_all, flags);
  hipLaunchKernelGGL(setup1, dim3(2048), dim3(64), 0, stream,
                     Wih, encW, encb, bih, bhh, Wcat, b2);
  hipLaunchKernelGGL(lstm_persist, dim3(128), dim3(512), 0, stream,
                     xT, Wcat, Wih_bf, b2, b_ar, h_all, flags);
  hipLaunchKernelGGL(final_proj, dim3(703), dim3(256), 0, stream,
                     h_all, decW_bf, decb, out);
}